// Round 2
// baseline (489.003 us; speedup 1.0000x reference)
//
#include <hip/hip_runtime.h>

// WindowMultiHeadAttention: b=4, n=4096, d=1024, H=16, dk=64, WIN=64, nw=64.
// R2: revert GEMM to the proven 128x128/BK32 structure (R0: 48us/GEMM, good
// XCD swizzle) and FUSE the fp32->bf16 conversion into the GEMM A-path
// (reg-staged, T14 split: loads issued before MFMA, cvt+ds_write after;
// single barrier per K-step via LDS double-buffer). Eliminates the three
// 96-MB cvt passes and their launches entirely. Final GEMM reg-stages Wo
// fp32 as its B operand, so only Wq/Wk/Wv are pre-converted (6.3 MB, into
// d_out's upper half -- dead until the final fp32 C overwrites it).
//
// Buffer plan:
//   d_out lower half : Xq (bf16)      -> clobbered by final fp32 C (Xq dead)
//   d_out upper half : Wb3 (Wq/Wk/Wv bf16, 6.3 MB) -> dead at final gemm
//   ws base  (33.5M) : Xo
//   ws +33.5M        : Xk;  ws +67M : Xv
//   inputs never written.

typedef unsigned short u16;
typedef unsigned int u32;
typedef __bf16 bf16x8 __attribute__((ext_vector_type(8)));
typedef float f32x4 __attribute__((ext_vector_type(4)));
typedef u16 u16x8 __attribute__((ext_vector_type(8)));

__device__ __forceinline__ u16 f2bf(float f) {
  u32 u = __builtin_bit_cast(u32, f);
  u += 0x7fffu + ((u >> 16) & 1u);  // RNE
  return (u16)(u >> 16);
}

__device__ __forceinline__ u16x8 cvt2(float4 a, float4 b) {
  u16x8 r;
  r[0] = f2bf(a.x); r[1] = f2bf(a.y); r[2] = f2bf(a.z); r[3] = f2bf(a.w);
  r[4] = f2bf(b.x); r[5] = f2bf(b.y); r[6] = f2bf(b.z); r[7] = f2bf(b.w);
  return r;
}

// Wq/Wk/Wv fp32 -> bf16, 1M elems each.
__global__ __launch_bounds__(256) void cvtw3_kernel(
    const float* __restrict__ Wq, const float* __restrict__ Wk,
    const float* __restrict__ Wv, u16* __restrict__ dst) {
  const float* src = (blockIdx.z == 0) ? Wq : (blockIdx.z == 1) ? Wk : Wv;
  const size_t i = ((size_t)blockIdx.x * 256 + threadIdx.x) * 8;
  const float4 a = *(const float4*)(src + i);
  const float4 b = *(const float4*)(src + i + 4);
  *(u16x8*)(dst + (size_t)blockIdx.z * 1048576 + i) = cvt2(a, b);
}

__device__ __forceinline__ void cp16(const u16* g, u16* l) {
  // async global->LDS, 16B/lane; LDS dst = wave-uniform base + lane*16.
  __builtin_amdgcn_global_load_lds((const __attribute__((address_space(1))) void*)g,
                                   (__attribute__((address_space(3))) void*)l, 16, 0, 0);
}

// C[M,N] = A[M,K]*B[N,K]^T, M=16384, N=K=1024. 128x128 tile, BK=32,
// 4 waves 2x2, 1024 blocks. XCD swizzle: XCD x owns m-tiles [x*16,x*16+16),
// n fastest -> per-XCD L2 working set ~4 MB (R0-proven FETCH 26.5 MB).
// AF32/BF32: that operand is fp32 in global, reg-staged + converted to bf16
// (T14 split). Otherwise bf16 via async cp16. LDS double-buffered; ONE
// __syncthreads per K-step (stage writes go to the alternate buffer).
template <int AF32, int BF32, int CF32>
__global__ __launch_bounds__(256, 2) void gemm_t_kernel(
    const void* __restrict__ Av, const void* __restrict__ Bv,
    void* __restrict__ Cv) {
  constexpr int N = 1024, K = 1024;
  __shared__ u16 lA[2][128 * 32];
  __shared__ u16 lB[2][128 * 32];
  const int tid = threadIdx.x;
  const int lane = tid & 63, w = tid >> 6;
  const int quad = lane >> 4, lr = lane & 15;
  const int lid = blockIdx.x;
  const int xcd = lid & 7, slot = lid >> 3;
  const int m0 = (xcd * 16 + (slot >> 3)) * 128;
  const int n0 = (slot & 7) * 128;
  const int wr = (w >> 1) * 64, wc = (w & 1) * 64;

  // 512 x 16B slots per 128x32 bf16 tile; thread owns slots ch1, ch2.
  // slot ch -> LDS u16 idx ch*8 = row (ch>>2), cols (ch&3)*8..+8.
  const int ch1 = tid, ch2 = tid + 256;

  const u16* A16 = (const u16*)Av;
  const float* A32 = (const float*)Av;
  const u16* B16 = (const u16*)Bv;
  const float* B32 = (const float*)Bv;

  const u16* Ag1 = A16 + (size_t)(m0 + (ch1 >> 2)) * K + (ch1 & 3) * 8;
  const u16* Ag2 = A16 + (size_t)(m0 + (ch2 >> 2)) * K + (ch2 & 3) * 8;
  const u16* Bg1 = B16 + (size_t)(n0 + (ch1 >> 2)) * K + (ch1 & 3) * 8;
  const u16* Bg2 = B16 + (size_t)(n0 + (ch2 >> 2)) * K + (ch2 & 3) * 8;
  const float* Af1 = A32 + (size_t)(m0 + (ch1 >> 2)) * K + (ch1 & 3) * 8;
  const float* Af2 = A32 + (size_t)(m0 + (ch2 >> 2)) * K + (ch2 & 3) * 8;
  const float* Bf1 = B32 + (size_t)(n0 + (ch1 >> 2)) * K + (ch1 & 3) * 8;
  const float* Bf2 = B32 + (size_t)(n0 + (ch2 >> 2)) * K + (ch2 & 3) * 8;

  float4 fA0, fA1, fA2, fA3, fB0, fB1, fB2, fB3;

  // Prologue: stage K-tile 0 into buf 0.
  if constexpr (AF32) {
    fA0 = *(const float4*)(Af1);     fA1 = *(const float4*)(Af1 + 4);
    fA2 = *(const float4*)(Af2);     fA3 = *(const float4*)(Af2 + 4);
    *(u16x8*)&lA[0][ch1 * 8] = cvt2(fA0, fA1);
    *(u16x8*)&lA[0][ch2 * 8] = cvt2(fA2, fA3);
  } else {
    cp16(Ag1, &lA[0][ch1 * 8]);
    cp16(Ag2, &lA[0][ch2 * 8]);
  }
  if constexpr (BF32) {
    fB0 = *(const float4*)(Bf1);     fB1 = *(const float4*)(Bf1 + 4);
    fB2 = *(const float4*)(Bf2);     fB3 = *(const float4*)(Bf2 + 4);
    *(u16x8*)&lB[0][ch1 * 8] = cvt2(fB0, fB1);
    *(u16x8*)&lB[0][ch2 * 8] = cvt2(fB2, fB3);
  } else {
    cp16(Bg1, &lB[0][ch1 * 8]);
    cp16(Bg2, &lB[0][ch2 * 8]);
  }
  __syncthreads();

  f32x4 acc[4][4] = {};
#pragma unroll 1
  for (int t = 0; t < 32; ++t) {
    const int cur = t & 1, nxt = cur ^ 1;
    const int k1 = (t + 1) * 32;
    const bool more = (t < 31);
    // Issue next-tile global traffic FIRST (longest latency).
    if (more) {
      if constexpr (AF32) {
        fA0 = *(const float4*)(Af1 + k1); fA1 = *(const float4*)(Af1 + k1 + 4);
        fA2 = *(const float4*)(Af2 + k1); fA3 = *(const float4*)(Af2 + k1 + 4);
      } else {
        cp16(Ag1 + k1, &lA[nxt][ch1 * 8]);
        cp16(Ag2 + k1, &lA[nxt][ch2 * 8]);
      }
      if constexpr (BF32) {
        fB0 = *(const float4*)(Bf1 + k1); fB1 = *(const float4*)(Bf1 + k1 + 4);
        fB2 = *(const float4*)(Bf2 + k1); fB3 = *(const float4*)(Bf2 + k1 + 4);
      } else {
        cp16(Bg1 + k1, &lB[nxt][ch1 * 8]);
        cp16(Bg2 + k1, &lB[nxt][ch2 * 8]);
      }
    }
    // Current-tile fragments + MFMA.
    bf16x8 afr[4], bfr[4];
#pragma unroll
    for (int mi = 0; mi < 4; ++mi)
      afr[mi] = *(const bf16x8*)&lA[cur][(wr + mi * 16 + lr) * 32 + quad * 8];
#pragma unroll
    for (int ni = 0; ni < 4; ++ni)
      bfr[ni] = *(const bf16x8*)&lB[cur][(wc + ni * 16 + lr) * 32 + quad * 8];
#pragma unroll
    for (int mi = 0; mi < 4; ++mi)
#pragma unroll
      for (int ni = 0; ni < 4; ++ni)
        acc[mi][ni] = __builtin_amdgcn_mfma_f32_16x16x32_bf16(
            afr[mi], bfr[ni], acc[mi][ni], 0, 0, 0);
    // Convert+write the prefetched fp32 regs into the alternate buffer
    // (fp32 load latency was hidden under the MFMA burst).
    if (more) {
      if constexpr (AF32) {
        *(u16x8*)&lA[nxt][ch1 * 8] = cvt2(fA0, fA1);
        *(u16x8*)&lA[nxt][ch2 * 8] = cvt2(fA2, fA3);
      }
      if constexpr (BF32) {
        *(u16x8*)&lB[nxt][ch1 * 8] = cvt2(fB0, fB1);
        *(u16x8*)&lB[nxt][ch2 * 8] = cvt2(fB2, fB3);
      }
    }
    __syncthreads();  // drains ds_writes (lgkm) + cp16s (vmcnt) for buf nxt
  }

  // Epilogue. C/D frag layout: row = quad*4+r, col = lr.
#pragma unroll
  for (int mi = 0; mi < 4; ++mi)
#pragma unroll
    for (int r = 0; r < 4; ++r) {
      const int row = m0 + wr + mi * 16 + quad * 4 + r;
      if constexpr (!CF32) {
        u16* dst = (u16*)Cv + (size_t)row * N + n0 + wc + lr;
#pragma unroll
        for (int ni = 0; ni < 4; ++ni) dst[ni * 16] = f2bf(acc[mi][ni][r]);
      } else {
        float* dst = (float*)Cv + (size_t)row * N + n0 + wc + lr;
#pragma unroll
        for (int ni = 0; ni < 4; ++ni) dst[ni * 16] = acc[mi][ni][r];
      }
    }
}

// One wave per (b, h, window). 64q x 64k x dk=64, bf16. LDS = P only (9.2 KB).
__global__ __launch_bounds__(64) void attn_win_kernel(
    const u16* __restrict__ Xq, const u16* __restrict__ Xk, const u16* __restrict__ Xv,
    u16* __restrict__ Xo) {
  __shared__ u16 P[64 * 72];  // [qp][kp], stride 72 keeps 16B row alignment
  const int bx = blockIdx.x;  // 0..4095
  const int wi = bx & 63, h = (bx >> 6) & 15, b = bx >> 10;
  const int lane = threadIdx.x & 63, quad = lane >> 4, lr = lane & 15;
  const size_t tb = (size_t)b * 4096 + wi * 64;  // window = 64 contiguous tokens
  const u16* qb = Xq + tb * 1024 + h * 64;
  const u16* kb = Xk + tb * 1024 + h * 64;
  const u16* vb = Xv + tb * 1024 + h * 64;

  // S = Q K^T: A-frag Q[m=lr+16mi][k=quad*8+j+32ks]; B-frag K[n=lr+16ni][k]
  bf16x8 aq[4][2], bk[4][2];
#pragma unroll
  for (int mi = 0; mi < 4; ++mi)
#pragma unroll
    for (int ks = 0; ks < 2; ++ks) {
      aq[mi][ks] = *(const bf16x8*)(qb + (size_t)(mi * 16 + lr) * 1024 + ks * 32 + quad * 8);
      bk[mi][ks] = *(const bf16x8*)(kb + (size_t)(mi * 16 + lr) * 1024 + ks * 32 + quad * 8);
    }
  f32x4 s[4][4];
#pragma unroll
  for (int mi = 0; mi < 4; ++mi)
#pragma unroll
    for (int ni = 0; ni < 4; ++ni) {
      f32x4 z = {0.f, 0.f, 0.f, 0.f};
      z = __builtin_amdgcn_mfma_f32_16x16x32_bf16(aq[mi][0], bk[ni][0], z, 0, 0, 0);
      s[mi][ni] = __builtin_amdgcn_mfma_f32_16x16x32_bf16(aq[mi][1], bk[ni][1], z, 0, 0, 0);
    }

  // V B-frags from global, overlapping the softmax latency:
  u16x8 bvr[2][4];
#pragma unroll
  for (int ks = 0; ks < 2; ++ks)
#pragma unroll
    for (int ci = 0; ci < 4; ++ci) {
      const u16* vc = vb + (size_t)(ks * 32 + quad * 8) * 1024 + ci * 16 + lr;
#pragma unroll
      for (int j = 0; j < 8; ++j) bvr[ks][ci][j] = vc[(size_t)j * 1024];
    }

  // softmax: row (quad*4+r of tile mi) spans this quad's 16 lanes x 4 ni regs
  const float sc = 0.125f;  // 1/sqrt(64)
#pragma unroll
  for (int mi = 0; mi < 4; ++mi)
#pragma unroll
    for (int r = 0; r < 4; ++r) {
      float mx = fmaxf(fmaxf(s[mi][0][r], s[mi][1][r]), fmaxf(s[mi][2][r], s[mi][3][r]));
#pragma unroll
      for (int m = 1; m < 16; m <<= 1) mx = fmaxf(mx, __shfl_xor(mx, m));
      float sum = 0.f;
#pragma unroll
      for (int ni = 0; ni < 4; ++ni) {
        float p = __expf((s[mi][ni][r] - mx) * sc);
        s[mi][ni][r] = p;
        sum += p;
      }
#pragma unroll
      for (int m = 1; m < 16; m <<= 1) sum += __shfl_xor(sum, m);
      const float inv = 1.f / sum;
#pragma unroll
      for (int ni = 0; ni < 4; ++ni) s[mi][ni][r] *= inv;
    }

  // P (C/D layout) -> LDS row-major
#pragma unroll
  for (int mi = 0; mi < 4; ++mi)
#pragma unroll
    for (int ni = 0; ni < 4; ++ni)
#pragma unroll
      for (int r = 0; r < 4; ++r)
        P[(mi * 16 + quad * 4 + r) * 72 + ni * 16 + lr] = f2bf(s[mi][ni][r]);
  __syncthreads();  // single wave: compiles to lgkmcnt drain

  // O = P V
  f32x4 o[4][4] = {};
#pragma unroll
  for (int ks = 0; ks < 2; ++ks) {
    bf16x8 ap[4];
#pragma unroll
    for (int mi = 0; mi < 4; ++mi)
      ap[mi] = *(const bf16x8*)&P[(mi * 16 + lr) * 72 + ks * 32 + quad * 8];
#pragma unroll
    for (int mi = 0; mi < 4; ++mi)
#pragma unroll
      for (int ci = 0; ci < 4; ++ci)
        o[mi][ci] = __builtin_amdgcn_mfma_f32_16x16x32_bf16(
            ap[mi], __builtin_bit_cast(bf16x8, bvr[ks][ci]), o[mi][ci], 0, 0, 0);
  }

  // reference permutation: out token = qp*64 + wi
#pragma unroll
  for (int mi = 0; mi < 4; ++mi)
#pragma unroll
    for (int r = 0; r < 4; ++r) {
      const int qp = mi * 16 + quad * 4 + r;
      u16* dst = Xo + ((size_t)b * 4096 + (size_t)qp * 64 + wi) * 1024 + h * 64 + lr;
#pragma unroll
      for (int ci = 0; ci < 4; ++ci) dst[ci * 16] = f2bf(o[mi][ci][r]);
    }
}

extern "C" void kernel_launch(void* const* d_in, const int* in_sizes, int n_in,
                              void* d_out, int out_size, void* d_ws, size_t ws_size,
                              hipStream_t stream) {
  (void)in_sizes; (void)n_in; (void)out_size; (void)ws_size;
  const float* q  = (const float*)d_in[0];
  const float* k  = (const float*)d_in[1];
  const float* v  = (const float*)d_in[2];
  const float* Wq = (const float*)d_in[3];
  const float* Wk = (const float*)d_in[4];
  const float* Wv = (const float*)d_in[5];
  const float* Wo = (const float*)d_in[6];

  constexpr size_t ELEMS = (size_t)16384 * 1024;
  u16* Xq  = (u16*)d_out;          // d_out lower half (bf16)
  u16* Wb3 = (u16*)d_out + ELEMS;  // d_out upper half: Wq/Wk/Wv bf16 (6.3 MB)
  u16* Xo  = (u16*)d_ws;
  u16* Xk  = Xo + ELEMS;
  u16* Xv  = Xk + ELEMS;

  cvtw3_kernel<<<dim3(512, 1, 3), 256, 0, stream>>>(Wq, Wk, Wv, Wb3);
  gemm_t_kernel<1, 0, 0><<<1024, 256, 0, stream>>>(q, Wb3,           Xq);
  gemm_t_kernel<1, 0, 0><<<1024, 256, 0, stream>>>(k, Wb3 + 1048576, Xk);
  gemm_t_kernel<1, 0, 0><<<1024, 256, 0, stream>>>(v, Wb3 + 2097152, Xv);
  attn_win_kernel<<<dim3(4096), 64, 0, stream>>>(Xq, Xk, Xv, Xo);
  gemm_t_kernel<0, 1, 1><<<1024, 256, 0, stream>>>(Xo, Wo, (float*)d_out);
}